// Round 12
// baseline (8129.327 us; speedup 1.0000x reference)
//
#include <hip/hip_runtime.h>

constexpr int SEQ   = 4096;  // timesteps
constexpr int IN    = 512;   // input size
constexpr int RS    = 2048;  // reservoir size
constexpr int GB    = 64;    // blocks in scan kernel
constexpr int BT    = 512;   // threads per block (8 waves x 4 rows)
constexpr int WAVES = BT / 64;
constexpr int RING  = 8;     // ring depth (epochs); skew bound <= 1
constexpr float INV_SQRT = 0.022097086912079612f; // 1/sqrt(2048)

// fast tanh: 1 - 2/(exp(2x)+1); exact saturation at +/-inf, ~1e-7 rel err.
__device__ __forceinline__ float fast_tanh(float x) {
    float e = __expf(2.0f * x);
    return 1.0f - 2.0f * __builtin_amdgcn_rcpf(e + 1.0f);
}

typedef unsigned long long u64;
#define AT_LOAD_U64(p)     __hip_atomic_load((p), __ATOMIC_RELAXED, __HIP_MEMORY_SCOPE_AGENT)
#define AT_STORE_U32(p, v) __hip_atomic_store((p), (v), __ATOMIC_RELAXED, __HIP_MEMORY_SCOPE_AGENT)

// ---------------------------------------------------------------------------
// Persistent scan, barrier-free dataflow, EPOCH-PARITY tags (R9 protocol)
// + LAST-WAVE PUBLISH: the 8th wave to finish its rows publishes the block's
// 128B line immediately (LDS ds_add_rtn arbitration) -- removes the second
// __syncthreads and the wave0 wake-up latency from the publish funnel.
//   state_t = tanh(W_in x_t + W_res s_{t-1}) / sqrt(RS)
// ring: RING x RS dwords in d_ws (64KB), memset-0 at call start (tag bit 0).
// Epoch e in row e%8, every dword tag bit0 = ((e>>3)&1)^1; stale epoch e-8
// carries the opposite tag; skew <= 1 rules out ABA at distance 16.
// Ordering: publisher's s_pub ds_reads feed the sc1 publish (data dep), so
// all step-t s_pub reads precede publish visibility, which precedes every
// wave's t+1 poll pass, which precedes any s_pub(t+1) write or t+1 atomic.
// Counter slot t&1 is reset by its own 8th arriver (the publisher) and next
// used only at t+2, behind a full rendezvous. No own-slice LDS shortcut:
// all threads poll the ring (detection is max-over-lines anyway).
// ---------------------------------------------------------------------------
__global__ __launch_bounds__(BT, 2)
void reservoir_scan_kernel(const float* __restrict__ x,
                           const float* __restrict__ init,
                           const float* __restrict__ W_in,
                           const float* __restrict__ W_res,
                           float* __restrict__ out,
                           unsigned* __restrict__ ring32) {
    __shared__ float s_state[RS];
    __shared__ float s_pub[32];
    __shared__ unsigned s_cnt[2];
    u64* ring = (u64*)ring32;
    const int bid  = blockIdx.x;
    const int tid  = threadIdx.x;
    const int wave = tid >> 6;
    const int lane = tid & 63;
    const int r0   = bid * 32 + wave * 4;     // first of this wave's 4 rows

    // --- W_res rows r0..r0+3 into registers (128 VGPR); pin ---
    float4 w[4][8];
#pragma unroll
    for (int r = 0; r < 4; ++r) {
        const float* wp = W_res + (size_t)(r0 + r) * RS + lane * 4;
#pragma unroll
        for (int j = 0; j < 8; ++j) w[r][j] = *(const float4*)(wp + j * 256);
    }
#pragma unroll
    for (int r = 0; r < 4; ++r)
#pragma unroll
        for (int j = 0; j < 8; ++j)
            asm volatile("" : "+v"(w[r][j].x), "+v"(w[r][j].y),
                              "+v"(w[r][j].z), "+v"(w[r][j].w));

    // --- W_in rows r0..r0+3, lane covers x-elems [8*lane, 8*lane+8) ---
    float4 wi[4][2];
#pragma unroll
    for (int r = 0; r < 4; ++r) {
        const float* wp = W_in + (size_t)(r0 + r) * IN + lane * 8;
        wi[r][0] = *(const float4*)wp;
        wi[r][1] = *(const float4*)(wp + 4);
    }
#pragma unroll
    for (int r = 0; r < 4; ++r)
#pragma unroll
        for (int j = 0; j < 2; ++j)
            asm volatile("" : "+v"(wi[r][j].x), "+v"(wi[r][j].y),
                              "+v"(wi[r][j].z), "+v"(wi[r][j].w));

    // --- init: counters zero; epoch 0 (wrap 0, tag 1) publish + out row 0 ---
    if (tid < 2) s_cnt[tid] = 0u;
    if (wave == 0 && lane < 32) {
        float v = init[bid * 32 + lane];
        out[bid * 32 + lane] = v;
        AT_STORE_U32(ring32 + bid * 32 + lane, __float_as_uint(v) | 1u);
    }
    __syncthreads();

    for (int t = 0; t < SEQ; ++t) {
        const size_t crow = (size_t)(t & (RING - 1)) * (RS / 2);        // u64
        const size_t prow = (size_t)((t + 1) & (RING - 1)) * RS;        // u32
        const unsigned tag_c = ((unsigned)(t >> 3) & 1u) ^ 1u;          // consume
        const unsigned tag_p = ((unsigned)((t + 1) >> 3) & 1u) ^ 1u;    // publish

        // --- prefetch x fragment for on-the-fly pre (overlaps the poll) ---
        const float* xp = x + (size_t)t * IN + lane * 8;
        float4 xv0 = *(const float4*)xp;
        float4 xv1 = *(const float4*)(xp + 4);

        // --- stage state row t into LDS: thread tid -> floats [4tid,4tid+4) ---
        {
            const u64* pp = ring + crow + 2 * tid;
            u64 v0 = AT_LOAD_U64(pp);
            u64 v1 = AT_LOAD_U64(pp + 1);
#define RDY(v) (((((unsigned)(v) ^ tag_c) | ((unsigned)((v) >> 32) ^ tag_c)) & 1u) == 0u)
            while (!(RDY(v0) && RDY(v1))) {
                v0 = AT_LOAD_U64(pp);
                v1 = AT_LOAD_U64(pp + 1);
            }
#undef RDY
            float4 sv;
            sv.x = __uint_as_float((unsigned)v0);
            sv.y = __uint_as_float((unsigned)(v0 >> 32));
            sv.z = __uint_as_float((unsigned)v1);
            sv.w = __uint_as_float((unsigned)(v1 >> 32));
            *(float4*)&s_state[4 * tid] = sv;
        }
        __syncthreads();

        // --- acc init = pre partial (W_in-frag . x-frag), then the dot ---
        float a0 = wi[0][0].x*xv0.x + wi[0][0].y*xv0.y + wi[0][0].z*xv0.z + wi[0][0].w*xv0.w
                 + wi[0][1].x*xv1.x + wi[0][1].y*xv1.y + wi[0][1].z*xv1.z + wi[0][1].w*xv1.w;
        float a1 = wi[1][0].x*xv0.x + wi[1][0].y*xv0.y + wi[1][0].z*xv0.z + wi[1][0].w*xv0.w
                 + wi[1][1].x*xv1.x + wi[1][1].y*xv1.y + wi[1][1].z*xv1.z + wi[1][1].w*xv1.w;
        float a2 = wi[2][0].x*xv0.x + wi[2][0].y*xv0.y + wi[2][0].z*xv0.z + wi[2][0].w*xv0.w
                 + wi[2][1].x*xv1.x + wi[2][1].y*xv1.y + wi[2][1].z*xv1.z + wi[2][1].w*xv1.w;
        float a3 = wi[3][0].x*xv0.x + wi[3][0].y*xv0.y + wi[3][0].z*xv0.z + wi[3][0].w*xv0.w
                 + wi[3][1].x*xv1.x + wi[3][1].y*xv1.y + wi[3][1].z*xv1.z + wi[3][1].w*xv1.w;
#pragma unroll
        for (int j = 0; j < 8; ++j) {
            const float4 sv = *(const float4*)&s_state[lane * 4 + j * 256];
            a0 += w[0][j].x * sv.x + w[0][j].y * sv.y + w[0][j].z * sv.z + w[0][j].w * sv.w;
            a1 += w[1][j].x * sv.x + w[1][j].y * sv.y + w[1][j].z * sv.z + w[1][j].w * sv.w;
            a2 += w[2][j].x * sv.x + w[2][j].y * sv.y + w[2][j].z * sv.z + w[2][j].w * sv.w;
            a3 += w[3][j].x * sv.x + w[3][j].y * sv.y + w[3][j].z * sv.z + w[3][j].w * sv.w;
        }

        // --- multi-value butterfly: 7 shfls; lane l ends with row (l&3) ---
        const bool p1 = (lane & 1) != 0;
        float k01 = p1 ? a1 : a0, s01 = p1 ? a0 : a1;
        k01 += __shfl_xor(s01, 1);
        float k23 = p1 ? a3 : a2, s23 = p1 ? a2 : a3;
        k23 += __shfl_xor(s23, 1);
        const bool p2 = (lane & 2) != 0;
        float kk = p2 ? k23 : k01, ss = p2 ? k01 : k23;
        kk += __shfl_xor(ss, 2);
        kk += __shfl_xor(kk, 4);
        kk += __shfl_xor(kk, 8);
        kk += __shfl_xor(kk, 16);
        kk += __shfl_xor(kk, 32);

        // --- lane<4: finish row r0+lane; stage decoded value for publish ---
        float sres = 0.f;
        if (lane < 4) {
            sres = fast_tanh(kk) * INV_SQRT;
            s_pub[wave * 4 + lane] = sres;
        }

        // --- last-arriving wave publishes (no barrier, no wave0 wakeup) ---
        unsigned old = 0;
        if (lane == 0) {
            __threadfence_block();               // s_pub write -> LDS complete
            old = atomicAdd(&s_cnt[t & 1], 1u);  // ds_add_rtn_u32
        }
        old = __shfl(old, 0);
        if (old == (unsigned)(WAVES - 1)) {
            if (lane == 0) s_cnt[t & 1] = 0;     // reset slot for step t+2
            if (lane < 32) {
                unsigned bits = (__float_as_uint(s_pub[lane]) & ~1u) | tag_p;
                AT_STORE_U32(ring32 + prow + bid * 32 + lane, bits);
            }
        }

        // --- out store AFTER publish: drains under next step's poll spin ---
        if (lane < 4)
            out[(size_t)(t + 1) * RS + r0 + lane] = sres;
    }
}

extern "C" void kernel_launch(void* const* d_in, const int* in_sizes, int n_in,
                              void* d_out, int out_size, void* d_ws, size_t ws_size,
                              hipStream_t stream) {
    const float* x     = (const float*)d_in[0];  // (4096, 512)
    const float* init  = (const float*)d_in[1];  // (2048,)
    const float* W_in  = (const float*)d_in[2];  // (2048, 512)
    const float* W_res = (const float*)d_in[3];  // (2048, 2048)
    float* out = (float*)d_out;                  // (4097, 2048)
    unsigned* ring = (unsigned*)d_ws;

    hipMemsetAsync(d_ws, 0, (size_t)RING * RS * sizeof(float), stream);

    void* args[] = { (void*)&x, (void*)&init, (void*)&W_in, (void*)&W_res,
                     (void*)&out, (void*)&ring };
    hipLaunchCooperativeKernel((void*)reservoir_scan_kernel,
                               dim3(GB), dim3(BT), args, 0, stream);
}

// Round 13
// 7554.593 us; speedup vs baseline: 1.0761x; 1.0761x over previous
//
#include <hip/hip_runtime.h>

constexpr int SEQ  = 4096;   // timesteps
constexpr int IN   = 512;    // input size
constexpr int RS   = 2048;   // reservoir size
constexpr int GB   = 64;     // blocks in scan kernel
constexpr int BT   = 512;    // threads per block (8 waves x 4 rows)
constexpr int RING = 8;      // ring depth (epochs); skew bound <= 1
constexpr float INV_SQRT = 0.022097086912079612f; // 1/sqrt(2048)

// fast tanh: 1 - 2/(exp(2x)+1); exact saturation at +/-inf, ~1e-7 rel err.
__device__ __forceinline__ float fast_tanh(float x) {
    float e = __expf(2.0f * x);
    return 1.0f - 2.0f * __builtin_amdgcn_rcpf(e + 1.0f);
}

typedef unsigned long long u64;
#define AT_LOAD_U64(p)     __hip_atomic_load((p), __ATOMIC_RELAXED, __HIP_MEMORY_SCOPE_AGENT)
#define AT_STORE_U32(p, v) __hip_atomic_store((p), (v), __ATOMIC_RELAXED, __HIP_MEMORY_SCOPE_AGENT)

// ---------------------------------------------------------------------------
// FINAL (R9 revert — best measured: 7560 us).
// Persistent scan, barrier-free dataflow with EPOCH-PARITY tags
// + on-the-fly input projection (no separate GEMM pass) + out-store moved
// off the publish critical path.
//   state_t = tanh(W_in x_t + W_res s_{t-1}) / sqrt(RS)
// ring: RING rows x RS dwords in d_ws, memset-0 at call start (tag bit 0).
// Epoch e lives in row e%8 with tag bit0 = ((e>>3)&1)^1; stale epoch e-8
// carries the opposite tag; skew <= 1 rules out ABA at distance 16.
// No zeroing, no vmcnt drain: publish = bare coalesced 128B sc1 store.
// Block b owns rows [b*32, b*32+32); wave w rows b*32 + 4w + {0..3}.
// Per step: [prefetch x-frag] || [poll 2 u64/thread -> LDS] -> sync1 ->
// acc = W_in-frag . x-frag (pre partial) + W-frags . LDS-state -> 7-shfl
// multi-value butterfly (reduces dot AND pre together) -> lane<4 tanh ->
// s_pub -> sync2 -> wave0 publishes 128B tagged line -> out store (drains
// under next step's poll spin).
// Ledger (12 rounds): grid.sync 10.4us/step -> relaxed-atomic barrier 5.1 ->
// dataflow ring 2.05 -> +parity tags 1.94 -> +8wx4r/GEMM-fusion 1.85 (this).
// Falsified: scattered/replicated/last-wave publish, poll pipelining/backoff,
// per-wave direct consume, XCD replicas (paper). Residual ~1.4us/step is the
// bare cross-XCD sc1-store -> IC-commit -> detect round trip: latency floor.
// ---------------------------------------------------------------------------
__global__ __launch_bounds__(BT, 2)
void reservoir_scan_kernel(const float* __restrict__ x,
                           const float* __restrict__ init,
                           const float* __restrict__ W_in,
                           const float* __restrict__ W_res,
                           float* __restrict__ out,
                           unsigned* __restrict__ ring32) {
    __shared__ float s_state[RS];
    __shared__ float s_pub[32];
    u64* ring = (u64*)ring32;
    const int bid  = blockIdx.x;
    const int tid  = threadIdx.x;
    const int wave = tid >> 6;
    const int lane = tid & 63;
    const int r0   = bid * 32 + wave * 4;     // first of this wave's 4 rows

    // --- W_res rows r0..r0+3 into registers (128 VGPR); pin ---
    float4 w[4][8];
#pragma unroll
    for (int r = 0; r < 4; ++r) {
        const float* wp = W_res + (size_t)(r0 + r) * RS + lane * 4;
#pragma unroll
        for (int j = 0; j < 8; ++j) w[r][j] = *(const float4*)(wp + j * 256);
    }
#pragma unroll
    for (int r = 0; r < 4; ++r)
#pragma unroll
        for (int j = 0; j < 8; ++j)
            asm volatile("" : "+v"(w[r][j].x), "+v"(w[r][j].y),
                              "+v"(w[r][j].z), "+v"(w[r][j].w));

    // --- W_in rows r0..r0+3, lane covers x-elems [8*lane, 8*lane+8) ---
    float4 wi[4][2];
#pragma unroll
    for (int r = 0; r < 4; ++r) {
        const float* wp = W_in + (size_t)(r0 + r) * IN + lane * 8;
        wi[r][0] = *(const float4*)wp;
        wi[r][1] = *(const float4*)(wp + 4);
    }
#pragma unroll
    for (int r = 0; r < 4; ++r)
#pragma unroll
        for (int j = 0; j < 2; ++j)
            asm volatile("" : "+v"(wi[r][j].x), "+v"(wi[r][j].y),
                              "+v"(wi[r][j].z), "+v"(wi[r][j].w));

    // --- epoch 0 (wrap 0, tag 1): out row 0 = init; publish; seed s_pub ---
    if (wave == 0 && lane < 32) {
        float v = init[bid * 32 + lane];
        out[bid * 32 + lane] = v;
        s_pub[lane] = v;
        AT_STORE_U32(ring32 + bid * 32 + lane, __float_as_uint(v) | 1u);
    }
    __syncthreads();

    for (int t = 0; t < SEQ; ++t) {
        const size_t crow = (size_t)(t & (RING - 1)) * (RS / 2);        // u64
        const size_t prow = (size_t)((t + 1) & (RING - 1)) * RS;        // u32
        const unsigned tag_c = ((unsigned)(t >> 3) & 1u) ^ 1u;          // consume
        const unsigned tag_p = ((unsigned)((t + 1) >> 3) & 1u) ^ 1u;    // publish

        // --- prefetch x fragment for on-the-fly pre (overlaps the poll) ---
        const float* xp = x + (size_t)t * IN + lane * 8;
        float4 xv0 = *(const float4*)xp;
        float4 xv1 = *(const float4*)(xp + 4);

        // --- stage state row t into LDS: thread tid -> floats [4tid,4tid+4) ---
        if ((tid >> 3) == bid) {
            const int k = tid & 7;
            *(float4*)&s_state[4 * tid] = *(const float4*)&s_pub[4 * k];
        } else {
            const u64* pp = ring + crow + 2 * tid;
            u64 v0 = AT_LOAD_U64(pp);
            u64 v1 = AT_LOAD_U64(pp + 1);
#define RDY(v) (((((unsigned)(v) ^ tag_c) | ((unsigned)((v) >> 32) ^ tag_c)) & 1u) == 0u)
            while (!(RDY(v0) && RDY(v1))) {
                v0 = AT_LOAD_U64(pp);
                v1 = AT_LOAD_U64(pp + 1);
            }
#undef RDY
            float4 sv;
            sv.x = __uint_as_float((unsigned)v0);
            sv.y = __uint_as_float((unsigned)(v0 >> 32));
            sv.z = __uint_as_float((unsigned)v1);
            sv.w = __uint_as_float((unsigned)(v1 >> 32));
            *(float4*)&s_state[4 * tid] = sv;
        }
        __syncthreads();

        // --- acc init = pre partial (W_in-frag . x-frag), then the dot ---
        float a0 = wi[0][0].x*xv0.x + wi[0][0].y*xv0.y + wi[0][0].z*xv0.z + wi[0][0].w*xv0.w
                 + wi[0][1].x*xv1.x + wi[0][1].y*xv1.y + wi[0][1].z*xv1.z + wi[0][1].w*xv1.w;
        float a1 = wi[1][0].x*xv0.x + wi[1][0].y*xv0.y + wi[1][0].z*xv0.z + wi[1][0].w*xv0.w
                 + wi[1][1].x*xv1.x + wi[1][1].y*xv1.y + wi[1][1].z*xv1.z + wi[1][1].w*xv1.w;
        float a2 = wi[2][0].x*xv0.x + wi[2][0].y*xv0.y + wi[2][0].z*xv0.z + wi[2][0].w*xv0.w
                 + wi[2][1].x*xv1.x + wi[2][1].y*xv1.y + wi[2][1].z*xv1.z + wi[2][1].w*xv1.w;
        float a3 = wi[3][0].x*xv0.x + wi[3][0].y*xv0.y + wi[3][0].z*xv0.z + wi[3][0].w*xv0.w
                 + wi[3][1].x*xv1.x + wi[3][1].y*xv1.y + wi[3][1].z*xv1.z + wi[3][1].w*xv1.w;
#pragma unroll
        for (int j = 0; j < 8; ++j) {
            const float4 sv = *(const float4*)&s_state[lane * 4 + j * 256];
            a0 += w[0][j].x * sv.x + w[0][j].y * sv.y + w[0][j].z * sv.z + w[0][j].w * sv.w;
            a1 += w[1][j].x * sv.x + w[1][j].y * sv.y + w[1][j].z * sv.z + w[1][j].w * sv.w;
            a2 += w[2][j].x * sv.x + w[2][j].y * sv.y + w[2][j].z * sv.z + w[2][j].w * sv.w;
            a3 += w[3][j].x * sv.x + w[3][j].y * sv.y + w[3][j].z * sv.z + w[3][j].w * sv.w;
        }

        // --- multi-value butterfly: 7 shfls; lane l ends with row (l&3) ---
        // (sums dot AND pre partials across all 64 lanes in one pass)
        const bool p1 = (lane & 1) != 0;
        float k01 = p1 ? a1 : a0, s01 = p1 ? a0 : a1;
        k01 += __shfl_xor(s01, 1);
        float k23 = p1 ? a3 : a2, s23 = p1 ? a2 : a3;
        k23 += __shfl_xor(s23, 1);
        const bool p2 = (lane & 2) != 0;
        float kk = p2 ? k23 : k01, ss = p2 ? k01 : k23;
        kk += __shfl_xor(ss, 2);
        kk += __shfl_xor(kk, 4);
        kk += __shfl_xor(kk, 8);
        kk += __shfl_xor(kk, 16);
        kk += __shfl_xor(kk, 32);

        // --- lane<4: finish row r0+lane; stage decoded value for publish ---
        float sres = 0.f;
        if (lane < 4) {
            sres = fast_tanh(kk) * INV_SQRT;
            s_pub[wave * 4 + lane] = sres;
        }
        __syncthreads();

        // --- publish FIRST: one coalesced 128B sc1 store with parity tag ---
        if (wave == 0 && lane < 32) {
            unsigned bits = __float_as_uint(s_pub[lane]);
            AT_STORE_U32(ring32 + prow + bid * 32 + lane,
                         (bits & ~1u) | tag_p);
        }

        // --- out store AFTER publish: drains under next step's poll spin ---
        if (lane < 4)
            out[(size_t)(t + 1) * RS + r0 + lane] = sres;
    }
}

extern "C" void kernel_launch(void* const* d_in, const int* in_sizes, int n_in,
                              void* d_out, int out_size, void* d_ws, size_t ws_size,
                              hipStream_t stream) {
    const float* x     = (const float*)d_in[0];  // (4096, 512)
    const float* init  = (const float*)d_in[1];  // (2048,)
    const float* W_in  = (const float*)d_in[2];  // (2048, 512)
    const float* W_res = (const float*)d_in[3];  // (2048, 2048)
    float* out = (float*)d_out;                  // (4097, 2048)
    unsigned* ring = (unsigned*)d_ws;

    hipMemsetAsync(d_ws, 0, (size_t)RING * RS * sizeof(float), stream);

    void* args[] = { (void*)&x, (void*)&init, (void*)&W_in, (void*)&W_res,
                     (void*)&out, (void*)&ring };
    hipLaunchCooperativeKernel((void*)reservoir_scan_kernel,
                               dim3(GB), dim3(BT), args, 0, stream);
}